// Round 5
// baseline (914.062 us; speedup 1.0000x reference)
//
#include <hip/hip_runtime.h>
#include <hip/hip_bf16.h>
#include <hip/hip_cooperative_groups.h>

namespace cg = cooperative_groups;

typedef __attribute__((ext_vector_type(8)))  short short8v;   // 8 bf16
typedef __attribute__((ext_vector_type(16))) float f32x16;

union ABfrag { short8v v; short s[8]; };

static __device__ __forceinline__ short f2bf(float f) {
    __hip_bfloat16 h = __float2bfloat16(f);   // RNE
    return __builtin_bit_cast(short, h);
}
static __device__ __forceinline__ float bf2f(short u) {
    unsigned v = (unsigned)(unsigned short)u << 16;
    return __builtin_bit_cast(float, v);
}

struct Params {
    const float* x;
    const int*   src;
    const int*   dst;
    const float* ea;
    const float* w1[4];  const float* b1[4];
    const float* w2[4];  const float* b2[4];
    const float* root[4]; const float* bias[4];
    short* xin;      // N x 8  bf16 (x[:,4:10] padded with zeros)
    short* featA;    // N x 32 bf16 (stored RELU'd)
    short* featB;    // N x 32 bf16
    short* msg;      // E x 32 bf16 ; layer 3 aliases this as float E x 2
    float* eaP;      // E x 4  (dst-sorted)
    int*   srcP;     // E      (dst-sorted)
    int*   rowptr;   // N+1
    int*   cnt;      // N (histogram, then scatter cursor)
    int*   bsum;     // up to 1024 block sums
    short* bswz;     // 110080 bf16: B-fragments, all 4 layers
    float* out;      // N x 2
    int N, E;
};

// bswz element offsets: L0 17 steps, L1/L2/L3 66 steps, 512 elems/step
// [0, 8704) [8704, 42496) [42496, 76288) [76288, 110080)

// ---------------------------------------------------------------------------
// Edge phase: wave = 32 edges, mfma_f32_32x32x16_bf16 over K = 32*INP (+ b2
// tail).  A built in-register with same kappa map as bswz; features bf16.
// C layout (m74/m101): col = lane&31 = o, row = (r&3) + 8*(r>>2) + 4*(lane>>5).
// ---------------------------------------------------------------------------
template<int INP, int OUT_C>
__device__ __forceinline__ void edge_phase(
    const short* __restrict__ feat, const float* __restrict__ w1,
    const float* __restrict__ b1, const short* __restrict__ bswz,
    const int* __restrict__ srcP, const float* __restrict__ eaP,
    short* __restrict__ msgb, float* __restrict__ msgf, int E)
{
    const int lane = threadIdx.x & 63;
    const int g = lane >> 5, o = lane & 31;
    const int gw = (blockIdx.x * blockDim.x + threadIdx.x) >> 6;
    const int nw = (gridDim.x * blockDim.x) >> 6;
    const int ntile = (E + 31) >> 5;
    const short8v* bp = (const short8v*)bswz;

    for (int wt = gw; wt < ntile; wt += nw) {
        const int e0 = wt * 32;
        const int er = e0 + (lane & 31);
        const int ec = er < E ? er : (E - 1);
        const int s  = srcP[ec];
        const float4 av = *(const float4*)(eaP + 4ll * ec);

        constexpr int NXR = (INP == 32) ? 16 : 8;
        float xr[NXR];
        if constexpr (INP == 32) {
            const short8v* fp = (const short8v*)(feat + (size_t)s * 32);
            short8v u0 = fp[g], u1 = fp[2 + g];
            #pragma unroll
            for (int j = 0; j < 8; ++j) { xr[j] = bf2f(u0[j]); xr[8 + j] = bf2f(u1[j]); }
        } else {
            short8v u0 = *(const short8v*)(feat + (size_t)s * 8);
            #pragma unroll
            for (int j = 0; j < 8; ++j) xr[j] = bf2f(u0[j]);
        }

        f32x16 C;
        #pragma unroll
        for (int i = 0; i < 16; ++i) C[i] = 0.f;

        if constexpr (INP == 32) {
            #pragma unroll 4
            for (int k = 0; k < 32; ++k) {
                float hk = fmaf(av.x, w1[k], b1[k]);
                hk = fmaf(av.y, w1[32 + k], hk);
                hk = fmaf(av.z, w1[64 + k], hk);
                hk = fmaf(av.w, w1[96 + k], hk);
                hk = fmaxf(hk, 0.f);
                ABfrag a0, a1;
                #pragma unroll
                for (int j = 0; j < 8; ++j) a0.s[j] = f2bf(hk * xr[j]);
                #pragma unroll
                for (int j = 0; j < 8; ++j) a1.s[j] = f2bf(hk * xr[8 + j]);
                C = __builtin_amdgcn_mfma_f32_32x32x16_bf16(a0.v, bp[(2*k  )*64 + lane], C, 0, 0, 0);
                C = __builtin_amdgcn_mfma_f32_32x32x16_bf16(a1.v, bp[(2*k+1)*64 + lane], C, 0, 0, 0);
            }
            ABfrag a;                                   // b2 tail, h == 1
            #pragma unroll
            for (int j = 0; j < 8; ++j) a.s[j] = f2bf(xr[j]);
            C = __builtin_amdgcn_mfma_f32_32x32x16_bf16(a.v, bp[64*64 + lane], C, 0, 0, 0);
            #pragma unroll
            for (int j = 0; j < 8; ++j) a.s[j] = f2bf(xr[8 + j]);
            C = __builtin_amdgcn_mfma_f32_32x32x16_bf16(a.v, bp[65*64 + lane], C, 0, 0, 0);
        } else {
            #pragma unroll 4
            for (int t = 0; t < 16; ++t) {
                const int k = 2 * t + g;
                float hk = fmaf(av.x, w1[k], b1[k]);
                hk = fmaf(av.y, w1[32 + k], hk);
                hk = fmaf(av.z, w1[64 + k], hk);
                hk = fmaf(av.w, w1[96 + k], hk);
                hk = fmaxf(hk, 0.f);
                ABfrag a;
                #pragma unroll
                for (int j = 0; j < 8; ++j) a.s[j] = f2bf(hk * xr[j]);
                C = __builtin_amdgcn_mfma_f32_32x32x16_bf16(a.v, bp[t*64 + lane], C, 0, 0, 0);
            }
            ABfrag a;                                   // b2 tail
            #pragma unroll
            for (int j = 0; j < 8; ++j) a.s[j] = (g == 0) ? f2bf(xr[j]) : (short)0;
            C = __builtin_amdgcn_mfma_f32_32x32x16_bf16(a.v, bp[16*64 + lane], C, 0, 0, 0);
        }

        if constexpr (OUT_C == 32) {
            if (e0 + 31 < E) {
                short* mp = msgb + (size_t)e0 * 32 + o;
                #pragma unroll
                for (int q = 0; q < 4; ++q)
                    #pragma unroll
                    for (int m = 0; m < 4; ++m)
                        mp[(size_t)(8*q + 4*g + m) * 32] = f2bf(C[4*q + m]);
            } else {
                #pragma unroll
                for (int q = 0; q < 4; ++q)
                    #pragma unroll
                    for (int m = 0; m < 4; ++m) {
                        int row = e0 + 8*q + 4*g + m;
                        if (row < E) msgb[(size_t)row * 32 + o] = f2bf(C[4*q + m]);
                    }
            }
        } else {
            if (o < OUT_C) {
                #pragma unroll
                for (int q = 0; q < 4; ++q)
                    #pragma unroll
                    for (int m = 0; m < 4; ++m) {
                        int row = e0 + 8*q + 4*g + m;
                        if (row < E) msgf[(size_t)row * OUT_C + o] = C[4*q + m];
                    }
            }
        }
    }
}

// ---------------------------------------------------------------------------
// Segment-sum + fused node term; features bf16 in, bf16 (relu'd) or f32 out.
// ---------------------------------------------------------------------------
template<int IN_C, int OUT_C, bool STORE_RELU, bool MSG_F32>
__device__ __forceinline__ void segsum_phase(
    const short* __restrict__ featin, const void* __restrict__ msg,
    const int* __restrict__ rowptr, const float* __restrict__ root,
    const float* __restrict__ bias, void* __restrict__ outp, int N)
{
    constexpr int CH = (OUT_C >= 8) ? 8 : OUT_C;
    constexpr int NC = OUT_C / CH;
    const int tid  = blockIdx.x * blockDim.x + threadIdx.x;
    const int nthr = gridDim.x * blockDim.x;
    for (int t = tid; t < N * NC; t += nthr) {
        const int v  = t / NC;
        const int c0 = (t % NC) * CH;
        float acc[CH];
        #pragma unroll
        for (int j = 0; j < CH; ++j) acc[j] = bias[c0 + j];

        if constexpr (IN_C == 32) {
            const short8v* fp = (const short8v*)(featin + (size_t)v * 32);
            #pragma unroll
            for (int blk = 0; blk < 4; ++blk) {
                short8v u = fp[blk];
                #pragma unroll
                for (int jj = 0; jj < 8; ++jj) {
                    float xi = bf2f(u[jj]);
                    int i = blk * 8 + jj;
                    #pragma unroll
                    for (int j = 0; j < CH; ++j)
                        acc[j] = fmaf(xi, root[i * OUT_C + c0 + j], acc[j]);
                }
            }
        } else {
            short8v u = *(const short8v*)(featin + (size_t)v * 8);
            #pragma unroll
            for (int i = 0; i < IN_C; ++i) {
                float xi = bf2f(u[i]);
                #pragma unroll
                for (int j = 0; j < CH; ++j)
                    acc[j] = fmaf(xi, root[i * OUT_C + c0 + j], acc[j]);
            }
        }

        const int r1 = rowptr[v + 1];
        for (int r = rowptr[v]; r < r1; ++r) {
            if constexpr (MSG_F32) {
                float2 m = ((const float2*)msg)[r];
                acc[0] += m.x; acc[1] += m.y;
            } else {
                short8v u = *(const short8v*)((const short*)msg + (size_t)r * 32 + c0);
                #pragma unroll
                for (int j = 0; j < CH; ++j) acc[j] += bf2f(u[j]);
            }
        }

        if constexpr (OUT_C == 2) {
            float2 o2; o2.x = acc[0]; o2.y = acc[1];
            ((float2*)outp)[v] = o2;
        } else {
            short8v o8;
            #pragma unroll
            for (int j = 0; j < CH; ++j)
                o8[j] = f2bf(STORE_RELU ? fmaxf(acc[j], 0.f) : acc[j]);
            *(short8v*)((short*)outp + (size_t)v * 32 + c0) = o8;
        }
    }
}

// ---------------------------------------------------------------------------
// The whole model in one cooperative kernel.  13 grid.sync()s.
// ---------------------------------------------------------------------------
__global__ __launch_bounds__(256, 4) void mega(Params p)
{
    cg::grid_group grid = cg::this_grid();
    const int tid  = blockIdx.x * 256 + threadIdx.x;
    const int nthr = gridDim.x * 256;
    __shared__ int lds[256];
    __shared__ int pref;

    // ---- P0: zero cnt, pack xin (bf16), build all B fragments ----
    for (int i = tid; i < p.N; i += nthr) p.cnt[i] = 0;
    for (int i = tid; i < p.N * 8; i += nthr) {
        int v = i >> 3, c = i & 7;
        float val = (c < 6) ? p.x[(size_t)v * 10 + 4 + c] : 0.f;
        p.xin[i] = f2bf(val);
    }
    for (int i = tid; i < 110080; i += nthr) {
        int layer, base, INP, IN_C, OUT_C;
        if (i < 8704)       { layer = 0; base = 0;     INP = 8;  IN_C = 6;  OUT_C = 32; }
        else if (i < 42496) { layer = 1; base = 8704;  INP = 32; IN_C = 32; OUT_C = 32; }
        else if (i < 76288) { layer = 2; base = 42496; INP = 32; IN_C = 32; OUT_C = 32; }
        else                { layer = 3; base = 76288; INP = 32; IN_C = 32; OUT_C = 2;  }
        int t2 = i - base;
        int j = t2 & 7, l = (t2 >> 3) & 63, t = t2 >> 9;
        int g = l >> 5, o = l & 31;
        int S_MAIN = 2 * INP;
        float v = 0.f;
        if (t < S_MAIN) {
            int kap = 16 * t + 8 * g + j;
            int k  = (INP == 8) ? (kap >> 3) : (kap >> 5);
            int ii = (INP == 8) ? (kap & 7)  : (kap & 31);
            if (ii < IN_C && o < OUT_C)
                v = p.w2[layer][(size_t)k * (IN_C * OUT_C) + ii * OUT_C + o];
        } else {
            int ii = 16 * (t - S_MAIN) + 8 * g + j;
            if (ii < IN_C && o < OUT_C)
                v = p.b2[layer][ii * OUT_C + o];
        }
        p.bswz[i] = f2bf(v);
    }
    grid.sync();

    // ---- P1: histogram of dst ----
    for (int e = tid; e < p.E; e += nthr) atomicAdd(&p.cnt[p.dst[e]], 1);
    grid.sync();

    // ---- P2: per-chunk sums ----
    const int nch = (p.N + 255) >> 8;
    for (int b = blockIdx.x; b < nch; b += gridDim.x) {
        int i = (b << 8) + threadIdx.x;
        int vv = (i < p.N) ? p.cnt[i] : 0;
        lds[threadIdx.x] = vv;
        __syncthreads();
        #pragma unroll
        for (int off = 128; off > 0; off >>= 1) {
            if (threadIdx.x < off) lds[threadIdx.x] += lds[threadIdx.x + off];
            __syncthreads();
        }
        if (threadIdx.x == 0) p.bsum[b] = lds[0];
        __syncthreads();
    }
    grid.sync();

    // ---- P3: final scan (inline block-prefix over bsum) -> rowptr, cursor ----
    for (int b = blockIdx.x; b < nch; b += gridDim.x) {
        int s = 0;
        for (int j2 = threadIdx.x; j2 < b; j2 += 256) s += p.bsum[j2];
        lds[threadIdx.x] = s;
        __syncthreads();
        #pragma unroll
        for (int off = 128; off > 0; off >>= 1) {
            if (threadIdx.x < off) lds[threadIdx.x] += lds[threadIdx.x + off];
            __syncthreads();
        }
        if (threadIdx.x == 0) pref = lds[0];
        __syncthreads();
        int i = (b << 8) + threadIdx.x;
        int vv = (i < p.N) ? p.cnt[i] : 0;
        lds[threadIdx.x] = vv;
        __syncthreads();
        for (int off = 1; off < 256; off <<= 1) {     // inclusive Hillis-Steele
            int u = (threadIdx.x >= off) ? lds[threadIdx.x - off] : 0;
            __syncthreads();
            lds[threadIdx.x] += u;
            __syncthreads();
        }
        int excl = lds[threadIdx.x] - vv + pref;
        if (i < p.N) {
            p.rowptr[i] = excl;
            p.cnt[i] = excl;                           // scatter cursor
            if (i == p.N - 1) p.rowptr[p.N] = excl + vv;
        }
        __syncthreads();
    }
    grid.sync();

    // ---- P4: scatter srcP / eaP in dst-sorted order ----
    for (int e = tid; e < p.E; e += nthr) {
        int pos = atomicAdd(&p.cnt[p.dst[e]], 1);
        p.srcP[pos] = p.src[e];
        float4 a = ((const float4*)p.ea)[e];
        ((float4*)p.eaP)[pos] = a;
    }
    grid.sync();

    // ---- layers ----
    edge_phase<8, 32>(p.xin, p.w1[0], p.b1[0], p.bswz + 0, p.srcP, p.eaP,
                      p.msg, nullptr, p.E);
    grid.sync();
    segsum_phase<6, 32, true, false>(p.xin, p.msg, p.rowptr, p.root[0], p.bias[0],
                                     p.featA, p.N);
    grid.sync();
    edge_phase<32, 32>(p.featA, p.w1[1], p.b1[1], p.bswz + 8704, p.srcP, p.eaP,
                       p.msg, nullptr, p.E);
    grid.sync();
    segsum_phase<32, 32, true, false>(p.featA, p.msg, p.rowptr, p.root[1], p.bias[1],
                                      p.featB, p.N);
    grid.sync();
    edge_phase<32, 32>(p.featB, p.w1[2], p.b1[2], p.bswz + 42496, p.srcP, p.eaP,
                       p.msg, nullptr, p.E);
    grid.sync();
    segsum_phase<32, 32, true, false>(p.featB, p.msg, p.rowptr, p.root[2], p.bias[2],
                                      p.featA, p.N);
    grid.sync();
    edge_phase<32, 2>(p.featA, p.w1[3], p.b1[3], p.bswz + 76288, p.srcP, p.eaP,
                      nullptr, (float*)p.msg, p.E);
    grid.sync();
    segsum_phase<32, 2, false, true>(p.featA, p.msg, p.rowptr, p.root[3], p.bias[3],
                                     p.out, p.N);
}

// ---------------------------------------------------------------------------
extern "C" void kernel_launch(void* const* d_in, const int* in_sizes, int n_in,
                              void* d_out, int out_size, void* d_ws, size_t ws_size,
                              hipStream_t stream)
{
    const float* x  = (const float*)d_in[0];
    const int*   ei = (const int*)d_in[1];
    const float* ea = (const float*)d_in[2];

    const int E = in_sizes[2] / 4;
    const int N = in_sizes[0] / 10;

    Params prm{};
    prm.x = x; prm.src = ei; prm.dst = ei + E; prm.ea = ea;
    for (int L = 0; L < 4; ++L) {
        prm.w1[L]   = (const float*)d_in[3 + 6*L + 0];
        prm.b1[L]   = (const float*)d_in[3 + 6*L + 1];
        prm.w2[L]   = (const float*)d_in[3 + 6*L + 2];
        prm.b2[L]   = (const float*)d_in[3 + 6*L + 3];
        prm.root[L] = (const float*)d_in[3 + 6*L + 4];
        prm.bias[L] = (const float*)d_in[3 + 6*L + 5];
    }

    char* w = (char*)d_ws;
    auto carve = [&](size_t bytes) {
        char* q = w; w += (bytes + 255) & ~(size_t)255; return (void*)q;
    };
    prm.xin    = (short*)carve((size_t)N * 8 * 2);
    prm.featA  = (short*)carve((size_t)N * 32 * 2);
    prm.featB  = (short*)carve((size_t)N * 32 * 2);
    prm.msg    = (short*)carve((size_t)E * 32 * 2);
    prm.eaP    = (float*)carve((size_t)E * 4 * 4);
    prm.srcP   = (int*)  carve((size_t)E * 4);
    prm.rowptr = (int*)  carve((size_t)(N + 1) * 4);
    prm.cnt    = (int*)  carve((size_t)N * 4);
    prm.bsum   = (int*)  carve(4096);
    prm.bswz   = (short*)carve(110080 * 2);
    prm.out    = (float*)d_out;
    prm.N = N; prm.E = E;

    // co-resident grid size: occupancy query (capture-safe) x 256 CUs, cap 1024
    int blkPerCU = 0;
    if (hipOccupancyMaxActiveBlocksPerMultiprocessor(
            &blkPerCU, (const void*)mega, 256, 0) != hipSuccess || blkPerCU < 1)
        blkPerCU = 2;
    int NBLK = blkPerCU * 256;
    if (NBLK > 1024) NBLK = 1024;

    void* args[] = { (void*)&prm };
    hipLaunchCooperativeKernel((const void*)mega, dim3(NBLK), dim3(256),
                               args, 0, stream);
}

// Round 6
// 195.089 us; speedup vs baseline: 4.6854x; 4.6854x over previous
//
#include <hip/hip_runtime.h>
#include <hip/hip_bf16.h>

typedef __attribute__((ext_vector_type(8)))  short short8v;   // 8 bf16
typedef __attribute__((ext_vector_type(16))) float f32x16;

union ABfrag { short8v v; short s[8]; };

static __device__ __forceinline__ short f2bf(float f) {
    __hip_bfloat16 h = __float2bfloat16(f);   // RNE
    return __builtin_bit_cast(short, h);
}
static __device__ __forceinline__ float bf2f(short u) {
    unsigned v = (unsigned)(unsigned short)u << 16;
    return __builtin_bit_cast(float, v);
}

// bswz element offsets: L0 17 steps, L1/L2/L3 66 steps, 512 bf16/step
// [0, 8704) [8704, 42496) [42496, 76288) [76288, 110080)
static constexpr int BSWZ_TOT = 110080;

struct Prm {
    const float* x;
    const float* w2[4]; const float* b2[4];
    const float* root0; const float* bias0;
    short* xin;      // N x 8 bf16 (x[:,4:10], zero-padded)
    short* bswz;     // all 4 layers' B fragments
    float* agg0;     // N x 32 f32, init = bias0 + x[:,4:10] @ root0
    int N;
};

// ---------------------------------------------------------------------------
// prep: block-role split — [0,430) build bswz ; [430,430+NB8) pack xin ;
// [430+NB8, …) init agg0 = bias0 + x[:,4:10] @ root0  (thread per node).
// Every output buffer fully overwritten each call -> replay-deterministic.
// ---------------------------------------------------------------------------
__global__ __launch_bounds__(256) void prep(Prm p, int NB8, int NBN)
{
    int b = blockIdx.x;
    if (b < 430) {                                   // ---- bswz ----
        int i = b * 256 + threadIdx.x;               // < 110080 exactly
        int layer, base, INP, IN_C, OUT_C;
        if (i < 8704)       { layer = 0; base = 0;     INP = 8;  IN_C = 6;  OUT_C = 32; }
        else if (i < 42496) { layer = 1; base = 8704;  INP = 32; IN_C = 32; OUT_C = 32; }
        else if (i < 76288) { layer = 2; base = 42496; INP = 32; IN_C = 32; OUT_C = 32; }
        else                { layer = 3; base = 76288; INP = 32; IN_C = 32; OUT_C = 2;  }
        int t2 = i - base;
        int j = t2 & 7, l = (t2 >> 3) & 63, t = t2 >> 9;
        int g = l >> 5, o = l & 31;
        int S_MAIN = 2 * INP;
        float v = 0.f;
        if (t < S_MAIN) {
            int kap = 16 * t + 8 * g + j;
            int k  = (INP == 8) ? (kap >> 3) : (kap >> 5);
            int ii = (INP == 8) ? (kap & 7)  : (kap & 31);
            if (ii < IN_C && o < OUT_C)
                v = p.w2[layer][(size_t)k * (IN_C * OUT_C) + ii * OUT_C + o];
        } else {
            int ii = 16 * (t - S_MAIN) + 8 * g + j;
            if (ii < IN_C && o < OUT_C)
                v = p.b2[layer][ii * OUT_C + o];
        }
        p.bswz[i] = f2bf(v);
    } else if (b < 430 + NB8) {                      // ---- pack xin ----
        int i = (b - 430) * 256 + threadIdx.x;
        if (i < p.N * 8) {
            int v = i >> 3, c = i & 7;
            float val = (c < 6) ? p.x[(size_t)v * 10 + 4 + c] : 0.f;
            p.xin[i] = f2bf(val);
        }
    } else {                                         // ---- agg0 init ----
        int v = (b - 430 - NB8) * 256 + threadIdx.x;
        if (v < p.N) {
            const float* xp = p.x + (size_t)v * 10 + 4;
            float xv[6];
            #pragma unroll
            for (int i = 0; i < 6; ++i) xv[i] = xp[i];
            float4 o4[8];
            #pragma unroll
            for (int q = 0; q < 8; ++q) {
                #pragma unroll
                for (int m = 0; m < 4; ++m) {
                    int o = 4 * q + m;
                    float a = p.bias0[o];
                    #pragma unroll
                    for (int i = 0; i < 6; ++i)
                        a = fmaf(xv[i], p.root0[i * 32 + o], a);
                    ((float*)&o4[q])[m] = a;
                }
            }
            float4* ap = (float4*)(p.agg0 + (size_t)v * 32);
            #pragma unroll
            for (int q = 0; q < 8; ++q) ap[q] = o4[q];
        }
    }
}

// ---------------------------------------------------------------------------
// Edge kernel: wave = 32 edges, mfma_f32_32x32x16_bf16 over K = 32*INP + b2
// tail.  A built in-register (same kappa map as bswz); features bf16.
// C layout (m74/m101): col = lane&31 = o, row = (r&3)+8*(r>>2)+4*(lane>>5).
// Epilogue: f32 atomics into agg (pre-initialized with node term + bias).
// ---------------------------------------------------------------------------
template<int INP, int OUT_C>
__global__ __launch_bounds__(256) void edge(
    const short* __restrict__ feat,
    const int*   __restrict__ src,
    const int*   __restrict__ dst,
    const float* __restrict__ ea,
    const float* __restrict__ w1,     // (4,32) row-major
    const float* __restrict__ b1,     // (32)
    const short* __restrict__ bswz,
    float* __restrict__ agg,          // row stride OUT_C
    int E)
{
    const int lane = threadIdx.x & 63;
    const int wid  = (blockIdx.x * 256 + threadIdx.x) >> 6;
    const int e0   = wid * 32;
    if (e0 >= E) return;
    const int g = lane >> 5, o = lane & 31;

    const int er = e0 + (lane & 31);
    const int ec = er < E ? er : (E - 1);
    const int s  = src[ec];
    const float4 av = *(const float4*)(ea + 4ll * ec);

    constexpr int NXR = (INP == 32) ? 16 : 8;
    float xr[NXR];
    if constexpr (INP == 32) {
        const short8v* fp = (const short8v*)(feat + (size_t)s * 32);
        short8v u0 = fp[g], u1 = fp[2 + g];
        #pragma unroll
        for (int j = 0; j < 8; ++j) { xr[j] = bf2f(u0[j]); xr[8 + j] = bf2f(u1[j]); }
    } else {
        short8v u0 = *(const short8v*)(feat + (size_t)s * 8);
        #pragma unroll
        for (int j = 0; j < 8; ++j) xr[j] = bf2f(u0[j]);
    }

    f32x16 C;
    #pragma unroll
    for (int i = 0; i < 16; ++i) C[i] = 0.f;

    const short8v* bp = (const short8v*)bswz;

    if constexpr (INP == 32) {
        #pragma unroll 4
        for (int k = 0; k < 32; ++k) {
            float hk = fmaf(av.x, w1[k], b1[k]);
            hk = fmaf(av.y, w1[32 + k], hk);
            hk = fmaf(av.z, w1[64 + k], hk);
            hk = fmaf(av.w, w1[96 + k], hk);
            hk = fmaxf(hk, 0.f);
            ABfrag a0, a1;
            #pragma unroll
            for (int j = 0; j < 8; ++j) a0.s[j] = f2bf(hk * xr[j]);
            #pragma unroll
            for (int j = 0; j < 8; ++j) a1.s[j] = f2bf(hk * xr[8 + j]);
            C = __builtin_amdgcn_mfma_f32_32x32x16_bf16(a0.v, bp[(2*k  )*64 + lane], C, 0, 0, 0);
            C = __builtin_amdgcn_mfma_f32_32x32x16_bf16(a1.v, bp[(2*k+1)*64 + lane], C, 0, 0, 0);
        }
        ABfrag a;                                   // b2 tail, h == 1
        #pragma unroll
        for (int j = 0; j < 8; ++j) a.s[j] = f2bf(xr[j]);
        C = __builtin_amdgcn_mfma_f32_32x32x16_bf16(a.v, bp[64*64 + lane], C, 0, 0, 0);
        #pragma unroll
        for (int j = 0; j < 8; ++j) a.s[j] = f2bf(xr[8 + j]);
        C = __builtin_amdgcn_mfma_f32_32x32x16_bf16(a.v, bp[65*64 + lane], C, 0, 0, 0);
    } else {
        #pragma unroll 4
        for (int t = 0; t < 16; ++t) {
            const int k = 2 * t + g;
            float hk = fmaf(av.x, w1[k], b1[k]);
            hk = fmaf(av.y, w1[32 + k], hk);
            hk = fmaf(av.z, w1[64 + k], hk);
            hk = fmaf(av.w, w1[96 + k], hk);
            hk = fmaxf(hk, 0.f);
            ABfrag a;
            #pragma unroll
            for (int j = 0; j < 8; ++j) a.s[j] = f2bf(hk * xr[j]);
            C = __builtin_amdgcn_mfma_f32_32x32x16_bf16(a.v, bp[t*64 + lane], C, 0, 0, 0);
        }
        ABfrag a;                                   // b2 tail
        #pragma unroll
        for (int j = 0; j < 8; ++j) a.s[j] = (g == 0) ? f2bf(xr[j]) : (short)0;
        C = __builtin_amdgcn_mfma_f32_32x32x16_bf16(a.v, bp[16*64 + lane], C, 0, 0, 0);
    }

    // epilogue: reg r=4q+m -> edge row e0+8q+4g+m, col o ; f32 atomics
    if (OUT_C == 32 || o < OUT_C) {
        #pragma unroll
        for (int q = 0; q < 4; ++q) {
            const int eb = e0 + 8 * q + 4 * g;
            if (eb + 3 < E) {
                const int4 dd = *(const int4*)(dst + eb);
                unsafeAtomicAdd(agg + (size_t)dd.x * OUT_C + o, C[4*q + 0]);
                unsafeAtomicAdd(agg + (size_t)dd.y * OUT_C + o, C[4*q + 1]);
                unsafeAtomicAdd(agg + (size_t)dd.z * OUT_C + o, C[4*q + 2]);
                unsafeAtomicAdd(agg + (size_t)dd.w * OUT_C + o, C[4*q + 3]);
            } else {
                #pragma unroll
                for (int m = 0; m < 4; ++m)
                    if (eb + m < E)
                        unsafeAtomicAdd(agg + (size_t)dst[eb + m] * OUT_C + o,
                                        C[4*q + m]);
            }
        }
    }
}

// ---------------------------------------------------------------------------
// fin: feat = relu(agg) as bf16 ; aggN = biasN + relu(agg) @ rootN (f32).
// Thread per node.  rootN/biasN wave-uniform -> scalar-cache loads.
// ---------------------------------------------------------------------------
template<int OUT_NEXT>
__global__ __launch_bounds__(256) void fin(
    const float* __restrict__ agg,    // N x 32
    const float* __restrict__ rootN,  // (32, OUT_NEXT)
    const float* __restrict__ biasN,  // (OUT_NEXT)
    short* __restrict__ feat,         // N x 32 bf16
    float* __restrict__ aggN,         // N x OUT_NEXT
    int N)
{
    int v = blockIdx.x * 256 + threadIdx.x;
    if (v >= N) return;

    float f[32];
    const float4* ap = (const float4*)(agg + (size_t)v * 32);
    #pragma unroll
    for (int q = 0; q < 8; ++q) {
        float4 a4 = ap[q];
        f[4*q+0] = fmaxf(a4.x, 0.f);
        f[4*q+1] = fmaxf(a4.y, 0.f);
        f[4*q+2] = fmaxf(a4.z, 0.f);
        f[4*q+3] = fmaxf(a4.w, 0.f);
    }

    short8v* fp = (short8v*)(feat + (size_t)v * 32);
    #pragma unroll
    for (int q = 0; q < 4; ++q) {
        short8v u;
        #pragma unroll
        for (int j = 0; j < 8; ++j) u[j] = f2bf(f[8*q + j]);
        fp[q] = u;
    }

    if constexpr (OUT_NEXT == 32) {
        float4 acc4[8];
        #pragma unroll
        for (int q = 0; q < 8; ++q) {
            #pragma unroll
            for (int m = 0; m < 4; ++m) {
                int o = 4*q + m;
                float a = biasN[o];
                #pragma unroll
                for (int i = 0; i < 32; ++i)
                    a = fmaf(f[i], rootN[i * 32 + o], a);
                ((float*)&acc4[q])[m] = a;
            }
        }
        float4* op = (float4*)(aggN + (size_t)v * 32);
        #pragma unroll
        for (int q = 0; q < 8; ++q) op[q] = acc4[q];
    } else {
        float a0 = biasN[0], a1 = biasN[1];
        #pragma unroll
        for (int i = 0; i < 32; ++i) {
            a0 = fmaf(f[i], rootN[i * 2 + 0], a0);
            a1 = fmaf(f[i], rootN[i * 2 + 1], a1);
        }
        float2 o2; o2.x = a0; o2.y = a1;
        ((float2*)aggN)[v] = o2;
    }
}

// ---------------------------------------------------------------------------
extern "C" void kernel_launch(void* const* d_in, const int* in_sizes, int n_in,
                              void* d_out, int out_size, void* d_ws, size_t ws_size,
                              hipStream_t stream)
{
    const float* x  = (const float*)d_in[0];
    const int*   ei = (const int*)d_in[1];
    const float* ea = (const float*)d_in[2];

    const int E = in_sizes[2] / 4;
    const int N = in_sizes[0] / 10;
    const int* src = ei;
    const int* dst = ei + E;

    const float* p[4][6];   // w1, b1, w2, b2, root, bias
    for (int L = 0; L < 4; ++L)
        for (int j = 0; j < 6; ++j)
            p[L][j] = (const float*)d_in[3 + 6 * L + j];

    char* w = (char*)d_ws;
    auto carve = [&](size_t bytes) {
        char* q = w; w += (bytes + 255) & ~(size_t)255; return (void*)q;
    };
    short* xin   = (short*)carve((size_t)N * 8 * 2);
    short* feat  = (short*)carve((size_t)N * 32 * 2);
    float* aggA  = (float*)carve((size_t)N * 32 * 4);
    float* aggB  = (float*)carve((size_t)N * 32 * 4);
    short* bswz  = (short*)carve((size_t)BSWZ_TOT * 2);
    float* out   = (float*)d_out;                    // N x 2, init'd by fin2

    Prm prm{};
    prm.x = x;
    for (int L = 0; L < 4; ++L) { prm.w2[L] = p[L][2]; prm.b2[L] = p[L][3]; }
    prm.root0 = p[0][4]; prm.bias0 = p[0][5];
    prm.xin = xin; prm.bswz = bswz; prm.agg0 = aggA; prm.N = N;

    const int NB8 = (N * 8 + 255) / 256;             // xin blocks
    const int NBN = (N + 255) / 256;                 // node blocks
    const int ntile = (E + 31) / 32;
    const int ebk = (ntile * 64 + 255) / 256;        // 4 wave-tiles / block

    // 8 dispatches total
    prep<<<430 + NB8 + NBN, 256, 0, stream>>>(prm, NB8, NBN);

    edge<8, 32><<<ebk, 256, 0, stream>>>(            // layer 0
        xin, src, dst, ea, p[0][0], p[0][1], bswz + 0, aggA, E);
    fin<32><<<NBN, 256, 0, stream>>>(aggA, p[1][4], p[1][5], feat, aggB, N);

    edge<32, 32><<<ebk, 256, 0, stream>>>(           // layer 1
        feat, src, dst, ea, p[1][0], p[1][1], bswz + 8704, aggB, E);
    fin<32><<<NBN, 256, 0, stream>>>(aggB, p[2][4], p[2][5], feat, aggA, N);

    edge<32, 32><<<ebk, 256, 0, stream>>>(           // layer 2
        feat, src, dst, ea, p[2][0], p[2][1], bswz + 42496, aggA, E);
    fin<2><<<NBN, 256, 0, stream>>>(aggA, p[3][4], p[3][5], feat, out, N);

    edge<32, 2><<<ebk, 256, 0, stream>>>(            // layer 3 -> d_out
        feat, src, dst, ea, p[3][0], p[3][1], bswz + 76288, out, E);
}

// Round 7
// 178.447 us; speedup vs baseline: 5.1223x; 1.0933x over previous
//
#include <hip/hip_runtime.h>
#include <hip/hip_fp16.h>

typedef __attribute__((ext_vector_type(8)))  _Float16 half8v;  // 8 f16 = 4 VGPR
typedef __attribute__((ext_vector_type(16))) float    f32x16;

// bswz element offsets: L0 17 steps, L1/L2/L3 66 steps, 512 f16/step
// [0, 8704) [8704, 42496) [42496, 76288) [76288, 110080)
static constexpr int BSWZ_TOT = 110080;

struct Prm {
    const float* x;
    const float* w2[4]; const float* b2[4];
    const float* root0; const float* bias0;
    _Float16* xin;   // N x 8 f16 (x[:,4:10], zero-padded)
    _Float16* bswz;  // all 4 layers' B fragments
    float* agg0;     // N x 32 f32, init = bias0 + x[:,4:10] @ root0
    int N;
};

// ---------------------------------------------------------------------------
// prep: block-role split — [0,430) build bswz ; [430,430+NB8) pack xin ;
// [430+NB8, …) init agg0 = bias0 + x[:,4:10] @ root0  (thread per node).
// ---------------------------------------------------------------------------
__global__ __launch_bounds__(256) void prep(Prm p, int NB8, int NBN)
{
    int b = blockIdx.x;
    if (b < 430) {                                   // ---- bswz ----
        int i = b * 256 + threadIdx.x;               // < 110080 exactly
        int layer, base, INP, IN_C, OUT_C;
        if (i < 8704)       { layer = 0; base = 0;     INP = 8;  IN_C = 6;  OUT_C = 32; }
        else if (i < 42496) { layer = 1; base = 8704;  INP = 32; IN_C = 32; OUT_C = 32; }
        else if (i < 76288) { layer = 2; base = 42496; INP = 32; IN_C = 32; OUT_C = 32; }
        else                { layer = 3; base = 76288; INP = 32; IN_C = 32; OUT_C = 2;  }
        int t2 = i - base;
        int j = t2 & 7, l = (t2 >> 3) & 63, t = t2 >> 9;
        int g = l >> 5, o = l & 31;
        int S_MAIN = 2 * INP;
        float v = 0.f;
        if (t < S_MAIN) {
            int kap = 16 * t + 8 * g + j;
            int k  = (INP == 8) ? (kap >> 3) : (kap >> 5);
            int ii = (INP == 8) ? (kap & 7)  : (kap & 31);
            if (ii < IN_C && o < OUT_C)
                v = p.w2[layer][(size_t)k * (IN_C * OUT_C) + ii * OUT_C + o];
        } else {
            int ii = 16 * (t - S_MAIN) + 8 * g + j;
            if (ii < IN_C && o < OUT_C)
                v = p.b2[layer][ii * OUT_C + o];
        }
        p.bswz[i] = (_Float16)v;
    } else if (b < 430 + NB8) {                      // ---- pack xin ----
        int i = (b - 430) * 256 + threadIdx.x;
        if (i < p.N * 8) {
            int v = i >> 3, c = i & 7;
            float val = (c < 6) ? p.x[(size_t)v * 10 + 4 + c] : 0.f;
            p.xin[i] = (_Float16)val;
        }
    } else {                                         // ---- agg0 init ----
        int v = (b - 430 - NB8) * 256 + threadIdx.x;
        if (v < p.N) {
            const float* xp = p.x + (size_t)v * 10 + 4;
            float xv[6];
            #pragma unroll
            for (int i = 0; i < 6; ++i) xv[i] = xp[i];
            float4 o4[8];
            #pragma unroll
            for (int q = 0; q < 8; ++q) {
                #pragma unroll
                for (int m = 0; m < 4; ++m) {
                    int o = 4 * q + m;
                    float a = p.bias0[o];
                    #pragma unroll
                    for (int i = 0; i < 6; ++i)
                        a = fmaf(xv[i], p.root0[i * 32 + o], a);
                    ((float*)&o4[q])[m] = a;
                }
            }
            float4* ap = (float4*)(p.agg0 + (size_t)v * 32);
            #pragma unroll
            for (int q = 0; q < 8; ++q) ap[q] = o4[q];
        }
    }
}

// ---------------------------------------------------------------------------
// Edge kernel: wave = 32 edges, mfma_f32_32x32x16_f16 over K = 32*INP + b2
// tail.  A-fragments built with packed f16 vector mul (v_pk_mul_f16):
// per k = 1 cvt + splat + 8 pk_mul (was ~37 f32 VALU ops with bf16).
// C layout (dtype-independent, m127/m128): col = lane&31, row = (r&3)+8*(r>>2)+4*(lane>>5).
// Epilogue: f32 atomics into agg (pre-initialized with node term + bias).
// ---------------------------------------------------------------------------
template<int INP, int OUT_C>
__global__ __launch_bounds__(256) void edge(
    const _Float16* __restrict__ feat,
    const int*      __restrict__ src,
    const int*      __restrict__ dst,
    const float*    __restrict__ ea,
    const float*    __restrict__ w1,     // (4,32) row-major
    const float*    __restrict__ b1,     // (32)
    const _Float16* __restrict__ bswz,
    float* __restrict__ agg,             // row stride OUT_C
    int E)
{
    const int lane = threadIdx.x & 63;
    const int wid  = (blockIdx.x * 256 + threadIdx.x) >> 6;
    const int e0   = wid * 32;
    if (e0 >= E) return;
    const int g = lane >> 5, o = lane & 31;

    const int er = e0 + (lane & 31);
    const int ec = er < E ? er : (E - 1);
    const int s  = src[ec];
    const float4 av = *(const float4*)(ea + 4ll * ec);

    // lane's x slice in f16: xh0 = x[8g..8g+7], xh1 = x[16+8g..16+8g+7]
    half8v xh0, xh1;
    if constexpr (INP == 32) {
        const half8v* fp = (const half8v*)(feat + (size_t)s * 32);
        xh0 = fp[g];
        xh1 = fp[2 + g];
    } else {
        xh0 = *(const half8v*)(feat + (size_t)s * 8);
    }

    f32x16 C;
    #pragma unroll
    for (int i = 0; i < 16; ++i) C[i] = 0.f;

    const half8v* bp = (const half8v*)bswz;

    if constexpr (INP == 32) {
        #pragma unroll 4
        for (int k = 0; k < 32; ++k) {
            float hk = fmaf(av.x, w1[k], b1[k]);
            hk = fmaf(av.y, w1[32 + k], hk);
            hk = fmaf(av.z, w1[64 + k], hk);
            hk = fmaf(av.w, w1[96 + k], hk);
            hk = fmaxf(hk, 0.f);
            const _Float16 hh = (_Float16)hk;
            half8v hs;
            #pragma unroll
            for (int j = 0; j < 8; ++j) hs[j] = hh;
            half8v a0 = hs * xh0;                       // 4x v_pk_mul_f16
            half8v a1 = hs * xh1;
            C = __builtin_amdgcn_mfma_f32_32x32x16_f16(a0, bp[(2*k  )*64 + lane], C, 0, 0, 0);
            C = __builtin_amdgcn_mfma_f32_32x32x16_f16(a1, bp[(2*k+1)*64 + lane], C, 0, 0, 0);
        }
        // b2 tail, h == 1: A = raw x fragments (zero VALU)
        C = __builtin_amdgcn_mfma_f32_32x32x16_f16(xh0, bp[64*64 + lane], C, 0, 0, 0);
        C = __builtin_amdgcn_mfma_f32_32x32x16_f16(xh1, bp[65*64 + lane], C, 0, 0, 0);
    } else {
        #pragma unroll 4
        for (int t = 0; t < 16; ++t) {
            const int k = 2 * t + g;                    // lane-dependent
            float hk = fmaf(av.x, w1[k], b1[k]);
            hk = fmaf(av.y, w1[32 + k], hk);
            hk = fmaf(av.z, w1[64 + k], hk);
            hk = fmaf(av.w, w1[96 + k], hk);
            hk = fmaxf(hk, 0.f);
            const _Float16 hh = (_Float16)hk;
            half8v hs;
            #pragma unroll
            for (int j = 0; j < 8; ++j) hs[j] = hh;
            half8v a = hs * xh0;
            C = __builtin_amdgcn_mfma_f32_32x32x16_f16(a, bp[t*64 + lane], C, 0, 0, 0);
        }
        half8v a;                                       // b2 tail
        if (g == 0) a = xh0;
        else {
            #pragma unroll
            for (int j = 0; j < 8; ++j) a[j] = (_Float16)0.f;
        }
        C = __builtin_amdgcn_mfma_f32_32x32x16_f16(a, bp[16*64 + lane], C, 0, 0, 0);
    }

    // epilogue: reg r=4q+m -> edge row e0+8q+4g+m, col o ; f32 atomics
    if (OUT_C == 32 || o < OUT_C) {
        #pragma unroll
        for (int q = 0; q < 4; ++q) {
            const int eb = e0 + 8 * q + 4 * g;
            if (eb + 3 < E) {
                const int4 dd = *(const int4*)(dst + eb);
                unsafeAtomicAdd(agg + (size_t)dd.x * OUT_C + o, C[4*q + 0]);
                unsafeAtomicAdd(agg + (size_t)dd.y * OUT_C + o, C[4*q + 1]);
                unsafeAtomicAdd(agg + (size_t)dd.z * OUT_C + o, C[4*q + 2]);
                unsafeAtomicAdd(agg + (size_t)dd.w * OUT_C + o, C[4*q + 3]);
            } else {
                #pragma unroll
                for (int m = 0; m < 4; ++m)
                    if (eb + m < E)
                        unsafeAtomicAdd(agg + (size_t)dst[eb + m] * OUT_C + o,
                                        C[4*q + m]);
            }
        }
    }
}

// ---------------------------------------------------------------------------
// fin: feat = relu(agg) as f16 ; aggN = biasN + relu(agg) @ rootN (f32).
// ---------------------------------------------------------------------------
template<int OUT_NEXT>
__global__ __launch_bounds__(256) void fin(
    const float* __restrict__ agg,    // N x 32
    const float* __restrict__ rootN,  // (32, OUT_NEXT)
    const float* __restrict__ biasN,  // (OUT_NEXT)
    _Float16* __restrict__ feat,      // N x 32 f16
    float* __restrict__ aggN,         // N x OUT_NEXT
    int N)
{
    int v = blockIdx.x * 256 + threadIdx.x;
    if (v >= N) return;

    float f[32];
    const float4* ap = (const float4*)(agg + (size_t)v * 32);
    #pragma unroll
    for (int q = 0; q < 8; ++q) {
        float4 a4 = ap[q];
        f[4*q+0] = fmaxf(a4.x, 0.f);
        f[4*q+1] = fmaxf(a4.y, 0.f);
        f[4*q+2] = fmaxf(a4.z, 0.f);
        f[4*q+3] = fmaxf(a4.w, 0.f);
    }

    half8v* fp = (half8v*)(feat + (size_t)v * 32);
    #pragma unroll
    for (int q = 0; q < 4; ++q) {
        half8v u;
        #pragma unroll
        for (int j = 0; j < 8; ++j) u[j] = (_Float16)f[8*q + j];
        fp[q] = u;
    }

    if constexpr (OUT_NEXT == 32) {
        float4 acc4[8];
        #pragma unroll
        for (int q = 0; q < 8; ++q) {
            #pragma unroll
            for (int m = 0; m < 4; ++m) {
                int o = 4*q + m;
                float a = biasN[o];
                #pragma unroll
                for (int i = 0; i < 32; ++i)
                    a = fmaf(f[i], rootN[i * 32 + o], a);
                ((float*)&acc4[q])[m] = a;
            }
        }
        float4* op = (float4*)(aggN + (size_t)v * 32);
        #pragma unroll
        for (int q = 0; q < 8; ++q) op[q] = acc4[q];
    } else {
        float a0 = biasN[0], a1 = biasN[1];
        #pragma unroll
        for (int i = 0; i < 32; ++i) {
            a0 = fmaf(f[i], rootN[i * 2 + 0], a0);
            a1 = fmaf(f[i], rootN[i * 2 + 1], a1);
        }
        float2 o2; o2.x = a0; o2.y = a1;
        ((float2*)aggN)[v] = o2;
    }
}

// ---------------------------------------------------------------------------
extern "C" void kernel_launch(void* const* d_in, const int* in_sizes, int n_in,
                              void* d_out, int out_size, void* d_ws, size_t ws_size,
                              hipStream_t stream)
{
    const float* x  = (const float*)d_in[0];
    const int*   ei = (const int*)d_in[1];
    const float* ea = (const float*)d_in[2];

    const int E = in_sizes[2] / 4;
    const int N = in_sizes[0] / 10;
    const int* src = ei;
    const int* dst = ei + E;

    const float* p[4][6];   // w1, b1, w2, b2, root, bias
    for (int L = 0; L < 4; ++L)
        for (int j = 0; j < 6; ++j)
            p[L][j] = (const float*)d_in[3 + 6 * L + j];

    char* w = (char*)d_ws;
    auto carve = [&](size_t bytes) {
        char* q = w; w += (bytes + 255) & ~(size_t)255; return (void*)q;
    };
    _Float16* xin  = (_Float16*)carve((size_t)N * 8 * 2);
    _Float16* feat = (_Float16*)carve((size_t)N * 32 * 2);
    float* aggA    = (float*)carve((size_t)N * 32 * 4);
    float* aggB    = (float*)carve((size_t)N * 32 * 4);
    _Float16* bswz = (_Float16*)carve((size_t)BSWZ_TOT * 2);
    float* out     = (float*)d_out;                  // N x 2, init'd by fin2

    Prm prm{};
    prm.x = x;
    for (int L = 0; L < 4; ++L) { prm.w2[L] = p[L][2]; prm.b2[L] = p[L][3]; }
    prm.root0 = p[0][4]; prm.bias0 = p[0][5];
    prm.xin = xin; prm.bswz = bswz; prm.agg0 = aggA; prm.N = N;

    const int NB8 = (N * 8 + 255) / 256;             // xin blocks
    const int NBN = (N + 255) / 256;                 // node blocks
    const int ntile = (E + 31) / 32;
    const int ebk = (ntile * 64 + 255) / 256;        // 4 wave-tiles / block

    // 8 dispatches total
    prep<<<430 + NB8 + NBN, 256, 0, stream>>>(prm, NB8, NBN);

    edge<8, 32><<<ebk, 256, 0, stream>>>(            // layer 0
        xin, src, dst, ea, p[0][0], p[0][1], bswz + 0, aggA, E);
    fin<32><<<NBN, 256, 0, stream>>>(aggA, p[1][4], p[1][5], feat, aggB, N);

    edge<32, 32><<<ebk, 256, 0, stream>>>(           // layer 1
        feat, src, dst, ea, p[1][0], p[1][1], bswz + 8704, aggB, E);
    fin<32><<<NBN, 256, 0, stream>>>(aggB, p[2][4], p[2][5], feat, aggA, N);

    edge<32, 32><<<ebk, 256, 0, stream>>>(           // layer 2
        feat, src, dst, ea, p[2][0], p[2][1], bswz + 42496, aggA, E);
    fin<2><<<NBN, 256, 0, stream>>>(aggA, p[3][4], p[3][5], feat, out, N);

    edge<32, 2><<<ebk, 256, 0, stream>>>(            // layer 3 -> d_out
        feat, src, dst, ea, p[3][0], p[3][1], bswz + 76288, out, E);
}